// Round 6
// baseline (266.731 us; speedup 1.0000x reference)
//
#include <hip/hip_runtime.h>
#include <hip/hip_bf16.h>
#include <math.h>

#define HH 128
#define WW 128
#define HWSZ (HH*WW)
#define CH 64
#define OC 64
#define NB 8

// ws layout: xT bf16 [b][h][w][c]      (16777216 B)
//            offs float4 [b][p]        (2097152 B)
//            wmT2 bf16 [k][oc][ch]     (73728 B)
#define XT_BYTES   (16777216u)
#define OFFS_BYTES (2097152u)

typedef __attribute__((ext_vector_type(8))) short bf16x8_t;   // 8 bf16 (4 VGPRs)
typedef __attribute__((ext_vector_type(4))) float f32x4_t;    // 4 fp32 acc

// ---------------- Kernel P: fused xT transpose + offsets + wmt ----------------
__global__ __launch_bounds__(256) void prep_kernel(
    const float* __restrict__ x,
    const float* __restrict__ w_main,
    const float* __restrict__ w_rot, const float* __restrict__ b_rot,
    const float* __restrict__ w_str, const float* __restrict__ b_str,
    const float* __restrict__ w_whl, const float* __restrict__ b_whl,
    __hip_bfloat16* __restrict__ xT, float4* __restrict__ offs,
    __hip_bfloat16* __restrict__ wmT2)
{
    const int i = blockIdx.x;
    const int t = threadIdx.x;
    if (i >= 512) {
        const int base = (i - 512) * 4096 + t * 16;
        #pragma unroll
        for (int j = 0; j < 16; ++j) {
            const int e = base + j;
            if (e < 36864) {
                const int k = e >> 12;
                const int r = e & 4095;
                const int o = r >> 6;
                const int c = r & 63;
                wmT2[e] = __float2bfloat16(w_main[(size_t)o * (CH * 9) + c * 9 + k]);
            }
        }
        return;
    }
    __shared__ float xs[2][8][4][WW];   // 16 KB ping-pong: 8 ch x 4 rows x 128 w
    const int b  = i & 7;               // XCD-affine
    const int h0 = (i >> 3) * 2;        // rows h0, h0+1
    const int r  = t >> 7;              // 0..1
    const int w  = t & 127;
    const int wl = max(w - 1, 0), wr2 = min(w + 1, WW - 1);
    const float ml = (w > 0) ? 1.f : 0.f, mr = (w < WW - 1) ? 1.f : 0.f;
    float a0 = 0.f, a1 = 0.f, a2 = 0.f, a3 = 0.f;
    const float* xb = x + (size_t)b * CH * HWSZ;

    int sch[4], srr[4], sw4[4];
    #pragma unroll
    for (int jj = 0; jj < 4; ++jj) {
        const int lin = t + jj * 256;
        sch[jj] = lin >> 7;
        const int rem = lin & 127;
        srr[jj] = rem >> 5;
        sw4[jj] = (rem & 31) * 4;
    }
    float4 rg[4];

    auto issue = [&](int c0) {
        #pragma unroll
        for (int jj = 0; jj < 4; ++jj) {
            const int grow = h0 - 1 + srr[jj];
            float4 v = make_float4(0.f, 0.f, 0.f, 0.f);
            if (grow >= 0 && grow < HH)
                v = *(const float4*)&xb[((size_t)(c0 + sch[jj]) * HH + grow) * WW + sw4[jj]];
            rg[jj] = v;
        }
    };
    auto commit = [&](int buf) {
        #pragma unroll
        for (int jj = 0; jj < 4; ++jj)
            *(float4*)&xs[buf][sch[jj]][srr[jj]][sw4[jj]] = rg[jj];
    };

    issue(0);
    commit(0);
    __syncthreads();
    for (int c = 0; c < 8; ++c) {
        if (c < 7) issue((c + 1) * 8);
        const int buf = c & 1;
        #pragma unroll
        for (int ch = 0; ch < 8; ++ch) {
            const int cc = c * 8 + ch;
            #pragma unroll
            for (int dy = 0; dy < 3; ++dy) {
                const float* row = &xs[buf][ch][r + dy][0];
                const float nl = row[wl] * ml;
                const float nc = row[w];
                const float nr = row[wr2] * mr;
                const int d0 = cc * 9 + dy * 3;
                a0 = fmaf(nl, w_rot[d0 + 0], a0); a0 = fmaf(nc, w_rot[d0 + 1], a0); a0 = fmaf(nr, w_rot[d0 + 2], a0);
                a1 = fmaf(nl, w_rot[576 + d0 + 0], a1); a1 = fmaf(nc, w_rot[576 + d0 + 1], a1); a1 = fmaf(nr, w_rot[576 + d0 + 2], a1);
                a2 = fmaf(nl, w_str[d0 + 0], a2); a2 = fmaf(nc, w_str[d0 + 1], a2); a2 = fmaf(nr, w_str[d0 + 2], a2);
                a3 = fmaf(nl, w_whl[d0 + 0], a3); a3 = fmaf(nc, w_whl[d0 + 1], a3); a3 = fmaf(nr, w_whl[d0 + 2], a3);
            }
        }
        {
            union { __hip_bfloat16 h[8]; uint4 q; } pk;
            #pragma unroll
            for (int ch = 0; ch < 8; ++ch)
                pk.h[ch] = __float2bfloat16(xs[buf][ch][r + 1][w]);
            *(uint4*)(xT + ((size_t)b * HWSZ + (h0 + r) * WW + w) * 64 + c * 8) = pk.q;
        }
        if (c < 7) commit((c + 1) & 1);
        __syncthreads();
    }
    float sv = a0 + b_rot[0], cvv = a1 + b_rot[1];
    const float inv = 1.0f / sqrtf(sv * sv + cvv * cvv + 1e-6f);
    const float rr = tanhf(a2 + b_str[0]) * 1.25f + 1.75f;   // A,B
    const float wq = tanhf(a3 + b_whl[0]) * 1.0f + 2.0f;     // C,D
    offs[(size_t)b * HWSZ + (h0 + r) * WW + w] = make_float4(sv * inv, cvv * inv, wq * rr, wq);
}

// ---------------- Kernel B: gather + MFMA, forced depth-2 tap pipeline ----------------
__device__ __forceinline__ void bf2x(unsigned int u, float& lo, float& hi) {
    union { unsigned int v; float f; } a, b;
    a.v = u << 16; b.v = u & 0xFFFF0000u;
    lo = a.f; hi = b.f;
}

struct Tap {
    uint4 q[8];                 // 4 corners x 2 slabs (16 B each)
    float w00, w01, w10, w11;
};

__device__ __forceinline__ void tap_load(
    int k, float hh, float wwf, float sv, float cv, float av, float wvl,
    const __hip_bfloat16* __restrict__ xb, int cb0, Tap& T)
{
    const float kyf = (float)(k / 3) - 1.f;
    const float kxf = (float)(k % 3) - 1.f;
    const float o0v = kyf * av;
    const float o1v = kxf * wvl;
    const float pyf = hh  + cv * o0v + sv * o1v;
    const float pxf = wwf - sv * o0v + cv * o1v;
    const float y0f = floorf(pyf), x0f = floorf(pxf);
    const float ly = pyf - y0f, lx = pxf - x0f;
    const int y0 = (int)y0f, x0i = (int)x0f;
    const int y1 = y0 + 1, x1 = x0i + 1;
    const bool vy0 = (y0 >= 0) && (y0 < HH);
    const bool vy1 = (y1 >= 0) && (y1 < HH);
    const bool vx0 = (x0i >= 0) && (x0i < WW);
    const bool vx1 = (x1 >= 0) && (x1 < WW);
    T.w00 = (1.f - ly) * (1.f - lx) * ((vy0 && vx0) ? 1.f : 0.f);
    T.w01 = (1.f - ly) * lx         * ((vy0 && vx1) ? 1.f : 0.f);
    T.w10 = ly * (1.f - lx)         * ((vy1 && vx0) ? 1.f : 0.f);
    T.w11 = ly * lx                 * ((vy1 && vx1) ? 1.f : 0.f);
    const int iy0 = min(max(y0, 0), HH - 1), iy1 = min(max(y1, 0), HH - 1);
    const int ix0 = min(max(x0i, 0), WW - 1), ix1 = min(max(x1, 0), WW - 1);
    const __hip_bfloat16* b00 = xb + (size_t)(iy0 * WW + ix0) * 64 + cb0;
    const __hip_bfloat16* b01 = xb + (size_t)(iy0 * WW + ix1) * 64 + cb0;
    const __hip_bfloat16* b10 = xb + (size_t)(iy1 * WW + ix0) * 64 + cb0;
    const __hip_bfloat16* b11 = xb + (size_t)(iy1 * WW + ix1) * 64 + cb0;
    T.q[0] = *(const uint4*)(b00);      T.q[1] = *(const uint4*)(b01);
    T.q[2] = *(const uint4*)(b10);      T.q[3] = *(const uint4*)(b11);
    T.q[4] = *(const uint4*)(b00 + 32); T.q[5] = *(const uint4*)(b01 + 32);
    T.q[6] = *(const uint4*)(b10 + 32); T.q[7] = *(const uint4*)(b11 + 32);
}

__device__ __forceinline__ void blend_mfma(
    const uint4& q00, const uint4& q01, const uint4& q10, const uint4& q11,
    float w00, float w01, float w10, float w11,
    const bf16x8_t& bf0, const bf16x8_t& bf1, const bf16x8_t& bf2v, const bf16x8_t& bf3,
    f32x4_t& acc0, f32x4_t& acc1, f32x4_t& acc2, f32x4_t& acc3)
{
    const unsigned int* u00 = (const unsigned int*)&q00;
    const unsigned int* u01 = (const unsigned int*)&q01;
    const unsigned int* u10 = (const unsigned int*)&q10;
    const unsigned int* u11 = (const unsigned int*)&q11;
    union { unsigned int u[4]; bf16x8_t v; } af;
    #pragma unroll
    for (int j = 0; j < 4; ++j) {
        float alo, ahi, blo, bhi, clo, chi, dlo, dhi;
        bf2x(u00[j], alo, ahi);
        bf2x(u01[j], blo, bhi);
        bf2x(u10[j], clo, chi);
        bf2x(u11[j], dlo, dhi);
        const float v_lo = w00 * alo + w01 * blo + w10 * clo + w11 * dlo;
        const float v_hi = w00 * ahi + w01 * bhi + w10 * chi + w11 * dhi;
        union { __hip_bfloat162 h; unsigned int u; } pk;
        pk.h = __float22bfloat162_rn(make_float2(v_lo, v_hi));
        af.u[j] = pk.u;
    }
    acc0 = __builtin_amdgcn_mfma_f32_16x16x32_bf16(af.v, bf0,  acc0, 0, 0, 0);
    acc1 = __builtin_amdgcn_mfma_f32_16x16x32_bf16(af.v, bf1,  acc1, 0, 0, 0);
    acc2 = __builtin_amdgcn_mfma_f32_16x16x32_bf16(af.v, bf2v, acc2, 0, 0, 0);
    acc3 = __builtin_amdgcn_mfma_f32_16x16x32_bf16(af.v, bf3,  acc3, 0, 0, 0);
}

__global__ __launch_bounds__(256, 3) void deform_kernel(
    const __hip_bfloat16* __restrict__ xT, const __hip_bfloat16* __restrict__ wmT2,
    const float4* __restrict__ offs, float* __restrict__ out)
{
    __shared__ float ots[64][67];   // epilogue only
    const int t  = threadIdx.x;
    const int wv = t >> 6;
    const int l  = t & 63;
    const int lm = l & 15;          // A-row (px) / B oc
    const int lg = l >> 4;          // 8-channel slab
    const int bi = blockIdx.x;      // 2048 blocks, 1-D
    const int b  = bi & 7;          // XCD-affine
    const int p0 = (bi >> 3) * 64;
    const int p  = p0 + wv * 16 + lm;
    const float hh  = (float)(p >> 7);
    const float wwf = (float)(p & (WW - 1));
    const float4 o4 = offs[(size_t)b * HWSZ + p];
    const float sv = o4.x, cv = o4.y, av = o4.z, wvl = o4.w;
    const __hip_bfloat16* xb = xT + (size_t)b * HWSZ * 64;
    const int cb0 = lg * 8;

    f32x4_t acc0 = {0.f, 0.f, 0.f, 0.f};
    f32x4_t acc1 = acc0, acc2 = acc0, acc3 = acc0;

    // Ring of 3 taps: taps k, k+1, k+2 in flight => ~16-24 outstanding loads/wave.
    Tap T[3];
    tap_load(0, hh, wwf, sv, cv, av, wvl, xb, cb0, T[0]);
    tap_load(1, hh, wwf, sv, cv, av, wvl, xb, cb0, T[1]);
    __builtin_amdgcn_sched_barrier(0);
    #pragma unroll
    for (int k = 0; k < 9; ++k) {
        if (k + 2 < 9)
            tap_load(k + 2, hh, wwf, sv, cv, av, wvl, xb, cb0, T[(k + 2) % 3]);
        // B-fragments for tap k (L1-hot, issued alongside the prefetch)
        const __hip_bfloat16* wp = wmT2 + ((size_t)k * 64 + lm) * 64 + cb0;
        const bf16x8_t s0b0 = *(const bf16x8_t*)(wp);
        const bf16x8_t s0b1 = *(const bf16x8_t*)(wp + 1024);
        const bf16x8_t s0b2 = *(const bf16x8_t*)(wp + 2048);
        const bf16x8_t s0b3 = *(const bf16x8_t*)(wp + 3072);
        const bf16x8_t s1b0 = *(const bf16x8_t*)(wp + 32);
        const bf16x8_t s1b1 = *(const bf16x8_t*)(wp + 1024 + 32);
        const bf16x8_t s1b2 = *(const bf16x8_t*)(wp + 2048 + 32);
        const bf16x8_t s1b3 = *(const bf16x8_t*)(wp + 3072 + 32);
        // Scheduling fence: prefetch issues above may not sink below.
        __builtin_amdgcn_sched_barrier(0);
        Tap& cur = T[k % 3];
        blend_mfma(cur.q[0], cur.q[1], cur.q[2], cur.q[3],
                   cur.w00, cur.w01, cur.w10, cur.w11,
                   s0b0, s0b1, s0b2, s0b3, acc0, acc1, acc2, acc3);
        blend_mfma(cur.q[4], cur.q[5], cur.q[6], cur.q[7],
                   cur.w00, cur.w01, cur.w10, cur.w11,
                   s1b0, s1b1, s1b2, s1b3, acc0, acc1, acc2, acc3);
        __builtin_amdgcn_sched_barrier(0);
    }
    // epilogue: C/D layout col=lane&15 (oc), row=(lane>>4)*4+reg (px)
    const int pxw = wv * 16 + lg * 4;
    #pragma unroll
    for (int rg2 = 0; rg2 < 4; ++rg2) {
        ots[pxw + rg2][ 0 + lm] = acc0[rg2];
        ots[pxw + rg2][16 + lm] = acc1[rg2];
        ots[pxw + rg2][32 + lm] = acc2[rg2];
        ots[pxw + rg2][48 + lm] = acc3[rg2];
    }
    __syncthreads();
    const int oo = t >> 2;
    const int q  = (t & 3) * 16;
    float4* dst = (float4*)&out[((size_t)b * OC + oo) * HWSZ + p0 + q];
    #pragma unroll
    for (int j2 = 0; j2 < 4; ++j2) {
        dst[j2] = make_float4(ots[q + j2 * 4 + 0][oo], ots[q + j2 * 4 + 1][oo],
                              ots[q + j2 * 4 + 2][oo], ots[q + j2 * 4 + 3][oo]);
    }
}

extern "C" void kernel_launch(void* const* d_in, const int* in_sizes, int n_in,
                              void* d_out, int out_size, void* d_ws, size_t ws_size,
                              hipStream_t stream)
{
    const float* x      = (const float*)d_in[0];
    const float* w_main = (const float*)d_in[1];
    const float* w_rot  = (const float*)d_in[2];
    const float* b_rot  = (const float*)d_in[3];
    const float* w_str  = (const float*)d_in[4];
    const float* b_str  = (const float*)d_in[5];
    const float* w_whl  = (const float*)d_in[6];
    const float* b_whl  = (const float*)d_in[7];
    float* out = (float*)d_out;

    char* ws = (char*)d_ws;
    __hip_bfloat16* xT   = (__hip_bfloat16*)ws;
    float4*         offs = (float4*)(ws + XT_BYTES);
    __hip_bfloat16* wmT2 = (__hip_bfloat16*)(ws + XT_BYTES + OFFS_BYTES);

    prep_kernel<<<dim3(521), 256, 0, stream>>>(
        x, w_main, w_rot, b_rot, w_str, b_str, w_whl, b_whl, xT, offs, wmT2);
    deform_kernel<<<dim3(2048), 256, 0, stream>>>(xT, wmT2, offs, out);
}

// Round 7
// 252.322 us; speedup vs baseline: 1.0571x; 1.0571x over previous
//
#include <hip/hip_runtime.h>
#include <hip/hip_bf16.h>
#include <math.h>

#define HH 128
#define WW 128
#define HWSZ (HH*WW)
#define CH 64
#define OC 64
#define NB 8
#define RG 28            // staged region dim: 8 + 2*10 halo
#define RPX (RG*RG)      // 784

// ws layout: xT bf16 [b][h][w][c]            (16777216 B)
//            offs float4-raw-sums [b][p]     (2097152 B)
//            wmT2 bf16 [k][oc][ch]           (73728 B)
#define XT_BYTES   (16777216u)
#define OFFS_BYTES (2097152u)

typedef __attribute__((ext_vector_type(8))) short bf16x8_t;   // 8 bf16
typedef __attribute__((ext_vector_type(4))) float f32x4_t;    // 4 fp32 acc

// ---------------- Kernel T: x NCHW fp32 -> xT NHWC bf16, + wmT2 tail ----------------
__global__ __launch_bounds__(256) void transpose_kernel(
    const float* __restrict__ x, const float* __restrict__ w_main,
    __hip_bfloat16* __restrict__ xT, __hip_bfloat16* __restrict__ wmT2)
{
    const int t = threadIdx.x;
    const int i = blockIdx.x;
    if (i >= 2048) {                 // wmT2: w_main [o][c][k] -> [k][o][c] bf16
        const int base = (i - 2048) * 4096 + t * 16;
        #pragma unroll
        for (int j = 0; j < 16; ++j) {
            const int e = base + j;
            const int k = e >> 12;
            const int r = e & 4095;
            const int o = r >> 6;
            const int c = r & 63;
            wmT2[e] = __float2bfloat16(w_main[(size_t)o * (CH * 9) + c * 9 + k]);
        }
        return;
    }
    __shared__ float tile[64][65];
    const int b = i & 7;             // XCD-affine
    const int j = i >> 3;
    const int h  = j >> 1;
    const int w0 = (j & 1) * 64;
    const float* xb = x + (size_t)b * CH * HWSZ + h * WW + w0;
    {
        const int w = t & 63, c0 = (t >> 6) * 16;
        #pragma unroll
        for (int jj = 0; jj < 16; ++jj)
            tile[c0 + jj][w] = xb[(size_t)(c0 + jj) * HWSZ + w];
    }
    __syncthreads();
    {
        const int c = t & 63, wq = t >> 6;
        __hip_bfloat16* o = xT + ((size_t)b * HWSZ + h * WW + w0) * 64;
        #pragma unroll
        for (int jj = 0; jj < 16; ++jj) {
            const int w = wq * 16 + jj;
            o[(size_t)w * 64 + c] = __float2bfloat16(tile[c][w]);
        }
    }
}

// ---------------- Kernel A: offsets partial sums (8 ch x 2 rows per block) ----------------
// offs holds RAW conv sums (no bias/norm/tanh) as float4 records; deform finishes.
__global__ __launch_bounds__(256) void offsets_kernel(
    const float* __restrict__ x,
    const float* __restrict__ w_rot,
    const float* __restrict__ w_str,
    const float* __restrict__ w_whl,
    float* __restrict__ offs)
{
    __shared__ float xs[8][4][WW];   // 16 KB: 8 ch x 4 halo rows x 128 w
    const int t  = threadIdx.x;
    const int i  = blockIdx.x;       // 4096 blocks
    const int b  = i & 7;            // XCD-affine
    const int rp = (i >> 3) & 63;
    const int cg = i >> 9;           // 0..7
    const int h0 = rp * 2;
    const int c0 = cg * 8;
    const float* xb = x + (size_t)b * CH * HWSZ;
    #pragma unroll
    for (int jj = 0; jj < 4; ++jj) {
        const int u   = t + jj * 256;       // < 1024
        const int ch  = u >> 7;
        const int rem = u & 127;
        const int row = rem >> 5;
        const int w4  = (rem & 31) * 4;
        const int grow = h0 - 1 + row;
        float4 v = make_float4(0.f, 0.f, 0.f, 0.f);
        if (grow >= 0 && grow < HH)
            v = *(const float4*)&xb[((size_t)(c0 + ch) * HH + grow) * WW + w4];
        *(float4*)&xs[ch][row][w4] = v;
    }
    __syncthreads();
    const int r = t >> 7, w = t & 127;
    const int wl = max(w - 1, 0), wr2 = min(w + 1, WW - 1);
    const float ml = (w > 0) ? 1.f : 0.f, mr = (w < WW - 1) ? 1.f : 0.f;
    float a0 = 0.f, a1 = 0.f, a2 = 0.f, a3 = 0.f;
    #pragma unroll
    for (int ch = 0; ch < 8; ++ch) {
        const int cc = c0 + ch;
        #pragma unroll
        for (int dy = 0; dy < 3; ++dy) {
            const float* row_ = &xs[ch][r + dy][0];
            const float nl = row_[wl] * ml;
            const float nc = row_[w];
            const float nr = row_[wr2] * mr;
            const int d0 = cc * 9 + dy * 3;
            a0 = fmaf(nl, w_rot[d0 + 0], a0); a0 = fmaf(nc, w_rot[d0 + 1], a0); a0 = fmaf(nr, w_rot[d0 + 2], a0);
            a1 = fmaf(nl, w_rot[576 + d0 + 0], a1); a1 = fmaf(nc, w_rot[576 + d0 + 1], a1); a1 = fmaf(nr, w_rot[576 + d0 + 2], a1);
            a2 = fmaf(nl, w_str[d0 + 0], a2); a2 = fmaf(nc, w_str[d0 + 1], a2); a2 = fmaf(nr, w_str[d0 + 2], a2);
            a3 = fmaf(nl, w_whl[d0 + 0], a3); a3 = fmaf(nc, w_whl[d0 + 1], a3); a3 = fmaf(nr, w_whl[d0 + 2], a3);
        }
    }
    float* op = &offs[(size_t)(b * HWSZ + (h0 + r) * WW + w) * 4];
    atomicAdd(op + 0, a0);
    atomicAdd(op + 1, a1);
    atomicAdd(op + 2, a2);
    atomicAdd(op + 3, a3);
}

// ---------------- Kernel B: LDS-staged gather + MFMA ----------------
__device__ __forceinline__ void bf2x(unsigned int u, float& lo, float& hi) {
    union { unsigned int v; float f; } a, b;
    a.v = u << 16; b.v = u & 0xFFFF0000u;
    lo = a.f; hi = b.f;
}

__device__ __forceinline__ void blend_mfma(
    const uint4& q00, const uint4& q01, const uint4& q10, const uint4& q11,
    float w00, float w01, float w10, float w11,
    const bf16x8_t& bf0, const bf16x8_t& bf1, const bf16x8_t& bf2v, const bf16x8_t& bf3,
    f32x4_t& acc0, f32x4_t& acc1, f32x4_t& acc2, f32x4_t& acc3)
{
    const unsigned int* u00 = (const unsigned int*)&q00;
    const unsigned int* u01 = (const unsigned int*)&q01;
    const unsigned int* u10 = (const unsigned int*)&q10;
    const unsigned int* u11 = (const unsigned int*)&q11;
    union { unsigned int u[4]; bf16x8_t v; } af;
    #pragma unroll
    for (int j = 0; j < 4; ++j) {
        float alo, ahi, blo, bhi, clo, chi, dlo, dhi;
        bf2x(u00[j], alo, ahi);
        bf2x(u01[j], blo, bhi);
        bf2x(u10[j], clo, chi);
        bf2x(u11[j], dlo, dhi);
        const float v_lo = w00 * alo + w01 * blo + w10 * clo + w11 * dlo;
        const float v_hi = w00 * ahi + w01 * bhi + w10 * chi + w11 * dhi;
        union { __hip_bfloat162 h; unsigned int u; } pk;
        pk.h = __float22bfloat162_rn(make_float2(v_lo, v_hi));
        af.u[j] = pk.u;
    }
    acc0 = __builtin_amdgcn_mfma_f32_16x16x32_bf16(af.v, bf0,  acc0, 0, 0, 0);
    acc1 = __builtin_amdgcn_mfma_f32_16x16x32_bf16(af.v, bf1,  acc1, 0, 0, 0);
    acc2 = __builtin_amdgcn_mfma_f32_16x16x32_bf16(af.v, bf2v, acc2, 0, 0, 0);
    acc3 = __builtin_amdgcn_mfma_f32_16x16x32_bf16(af.v, bf3,  acc3, 0, 0, 0);
}

__global__ __launch_bounds__(256, 3) void deform_kernel(
    const __hip_bfloat16* __restrict__ xT, const __hip_bfloat16* __restrict__ wmT2,
    const float* __restrict__ offs,
    const float* __restrict__ b_rot, const float* __restrict__ b_str,
    const float* __restrict__ b_whl, float* __restrict__ out)
{
    __shared__ union {
        uint4 xs[RPX * 4];      // 28*28 px * 64 B (32 ch bf16) = 50176 B
        float ots[64][67];      // epilogue
    } sh;
    const int t  = threadIdx.x;
    const int wv = t >> 6;
    const int l  = t & 63;
    const int lm = l & 15;          // A-row (px) / B oc
    const int lg = l >> 4;          // 8-channel slab within group
    const int i  = blockIdx.x;      // 2048 blocks
    const int b  = i & 7;           // XCD-affine
    const int tile = i >> 3;        // 0..255
    const int w0 = (tile & 15) * 8;
    const int h0 = (tile >> 4) * 8;
    const int pi = wv * 16 + lm;    // local px 0..63
    const int h = h0 + (pi >> 3);
    const int w = w0 + (pi & 7);
    // finish the offsets: raw sums + bias -> norm/tanh
    const float4 o4 = *(const float4*)&offs[(size_t)(b * HWSZ + h * WW + w) * 4];
    float sv = o4.x + b_rot[0], cv = o4.y + b_rot[1];
    const float inv = 1.0f / sqrtf(sv * sv + cv * cv + 1e-6f);
    sv *= inv; cv *= inv;
    const float rr  = tanhf(o4.z + b_str[0]) * 1.25f + 1.75f;   // A,B
    const float wq  = tanhf(o4.w + b_whl[0]) * 1.0f + 2.0f;     // C,D
    const float av  = wq * rr;
    const float wvl = wq;
    const float hh  = (float)h;
    const float wwf = (float)w;
    const __hip_bfloat16* xb = xT + (size_t)b * HWSZ * 64;

    f32x4_t acc0 = {0.f, 0.f, 0.f, 0.f};
    f32x4_t acc1 = acc0, acc2 = acc0, acc3 = acc0;

    for (int g = 0; g < 2; ++g) {
        __syncthreads();
        // stage 28x28 region, 32 channels of group g: 3136 16-B units, coalesced
        for (int u = t; u < RPX * 4; u += 256) {
            const int pxu = u >> 2, q = u & 3;
            const int lr = pxu / RG;
            const int lc = pxu - lr * RG;
            const int gy = min(max(h0 - 10 + lr, 0), HH - 1);
            const int gx = min(max(w0 - 10 + lc, 0), WW - 1);
            sh.xs[pxu * 4 + q] =
                *(const uint4*)(xb + (size_t)(gy * WW + gx) * 64 + g * 32 + q * 8);
        }
        __syncthreads();
        const int cb0 = g * 32 + lg * 8;
        #pragma unroll
        for (int k = 0; k < 9; ++k) {
            const float kyf = (float)(k / 3) - 1.f;
            const float kxf = (float)(k % 3) - 1.f;
            const float o0v = kyf * av;
            const float o1v = kxf * wvl;
            const float pyf = hh  + cv * o0v + sv * o1v;
            const float pxf = wwf - sv * o0v + cv * o1v;
            const float y0f = floorf(pyf), x0f = floorf(pxf);
            const float ly = pyf - y0f, lx = pxf - x0f;
            const int y0 = (int)y0f, x0i = (int)x0f;
            const int y1 = y0 + 1, x1 = x0i + 1;
            const bool vy0 = (y0 >= 0) && (y0 < HH);
            const bool vy1 = (y1 >= 0) && (y1 < HH);
            const bool vx0 = (x0i >= 0) && (x0i < WW);
            const bool vx1 = (x1 >= 0) && (x1 < WW);
            const float w00 = (1.f - ly) * (1.f - lx) * ((vy0 && vx0) ? 1.f : 0.f);
            const float w01 = (1.f - ly) * lx         * ((vy0 && vx1) ? 1.f : 0.f);
            const float w10 = ly * (1.f - lx)         * ((vy1 && vx0) ? 1.f : 0.f);
            const float w11 = ly * lx                 * ((vy1 && vx1) ? 1.f : 0.f);
            const int ly0 = min(max(y0, 0), HH - 1) - (h0 - 10);
            const int ly1 = min(max(y1, 0), HH - 1) - (h0 - 10);
            const int lx0 = min(max(x0i, 0), WW - 1) - (w0 - 10);
            const int lx1 = min(max(x1, 0), WW - 1) - (w0 - 10);
            const uint4 q00 = sh.xs[(ly0 * RG + lx0) * 4 + lg];
            const uint4 q01 = sh.xs[(ly0 * RG + lx1) * 4 + lg];
            const uint4 q10 = sh.xs[(ly1 * RG + lx0) * 4 + lg];
            const uint4 q11 = sh.xs[(ly1 * RG + lx1) * 4 + lg];
            const __hip_bfloat16* wp = wmT2 + ((size_t)k * 64 + lm) * 64 + cb0;
            const bf16x8_t bf0 = *(const bf16x8_t*)(wp);
            const bf16x8_t bf1 = *(const bf16x8_t*)(wp + 1024);
            const bf16x8_t bf2v = *(const bf16x8_t*)(wp + 2048);
            const bf16x8_t bf3 = *(const bf16x8_t*)(wp + 3072);
            blend_mfma(q00, q01, q10, q11, w00, w01, w10, w11,
                       bf0, bf1, bf2v, bf3, acc0, acc1, acc2, acc3);
        }
    }
    __syncthreads();
    // epilogue: C/D layout col=lane&15 (oc), row=(lane>>4)*4+reg (local px)
    const int pxw = wv * 16 + lg * 4;
    #pragma unroll
    for (int rg2 = 0; rg2 < 4; ++rg2) {
        sh.ots[pxw + rg2][ 0 + lm] = acc0[rg2];
        sh.ots[pxw + rg2][16 + lm] = acc1[rg2];
        sh.ots[pxw + rg2][32 + lm] = acc2[rg2];
        sh.ots[pxw + rg2][48 + lm] = acc3[rg2];
    }
    __syncthreads();
    const int oo = t >> 2;
    const int q  = (t & 3) * 16;
    #pragma unroll
    for (int j2 = 0; j2 < 4; ++j2) {
        const int px = q + j2 * 4;               // local px, 4 consecutive
        float4 v = make_float4(sh.ots[px + 0][oo], sh.ots[px + 1][oo],
                               sh.ots[px + 2][oo], sh.ots[px + 3][oo]);
        *(float4*)&out[((size_t)b * OC + oo) * HWSZ +
                       (h0 + (px >> 3)) * WW + w0 + (px & 7)] = v;
    }
}

extern "C" void kernel_launch(void* const* d_in, const int* in_sizes, int n_in,
                              void* d_out, int out_size, void* d_ws, size_t ws_size,
                              hipStream_t stream)
{
    const float* x      = (const float*)d_in[0];
    const float* w_main = (const float*)d_in[1];
    const float* w_rot  = (const float*)d_in[2];
    const float* b_rot  = (const float*)d_in[3];
    const float* w_str  = (const float*)d_in[4];
    const float* b_str  = (const float*)d_in[5];
    const float* w_whl  = (const float*)d_in[6];
    const float* b_whl  = (const float*)d_in[7];
    float* out = (float*)d_out;

    char* ws = (char*)d_ws;
    __hip_bfloat16* xT   = (__hip_bfloat16*)ws;
    float*          offs = (float*)(ws + XT_BYTES);
    __hip_bfloat16* wmT2 = (__hip_bfloat16*)(ws + XT_BYTES + OFFS_BYTES);

    hipMemsetAsync(offs, 0, OFFS_BYTES, stream);
    transpose_kernel<<<dim3(2057), 256, 0, stream>>>(x, w_main, xT, wmT2);
    offsets_kernel<<<dim3(4096), 256, 0, stream>>>(x, w_rot, w_str, w_whl, offs);
    deform_kernel<<<dim3(2048), 256, 0, stream>>>(xT, wmT2, offs,
                                                  b_rot, b_str, b_whl, out);
}

// Round 9
// 211.056 us; speedup vs baseline: 1.2638x; 1.1955x over previous
//
#include <hip/hip_runtime.h>
#include <hip/hip_bf16.h>
#include <hip/hip_fp16.h>
#include <math.h>

#define HH 128
#define WW 128
#define HWSZ (HH*WW)
#define CH 64
#define OC 64
#define NB 8
#define RG 28            // staged region dim: 8 + 2*10 halo
#define RPX (RG*RG)      // 784

// ws layout: xT fp16 [b][h][w][c]   (8*16384*64*2 = 16777216 B)
//            offs float4 [b][p]     (2097152 B)
//            wmT2 fp16 [k][oc][ch]  (36864*2 B)
#define XT_BYTES   (16777216u)   // R8 bug: was 8388608 -> offs/wmT2 aliased xT -> NaN
#define OFFS_BYTES (2097152u)
// d_out (33.5 MB) doubles as scratch for the 8 offset partials (16.8 MB)

typedef _Float16 f16x8 __attribute__((ext_vector_type(8)));   // 4 VGPRs
typedef __attribute__((ext_vector_type(4))) float f32x4_t;    // 4 fp32 acc

// ---------------- Kernel T: x NCHW fp32 -> xT NHWC fp16, + wmT2 tail ----------------
__global__ __launch_bounds__(256) void transpose_kernel(
    const float* __restrict__ x, const float* __restrict__ w_main,
    __half* __restrict__ xT, __half* __restrict__ wmT2)
{
    const int t = threadIdx.x;
    const int i = blockIdx.x;
    if (i >= 2048) {                 // wmT2: w_main [o][c][k] -> [k][o][c] fp16
        const int base = (i - 2048) * 4096 + t * 16;
        #pragma unroll
        for (int j = 0; j < 16; ++j) {
            const int e = base + j;
            const int k = e >> 12;
            const int r = e & 4095;
            const int o = r >> 6;
            const int c = r & 63;
            wmT2[e] = __float2half(w_main[(size_t)o * (CH * 9) + c * 9 + k]);
        }
        return;
    }
    __shared__ float tile[64][65];
    const int b = i & 7;             // XCD-affine
    const int j = i >> 3;
    const int h  = j >> 1;
    const int w0 = (j & 1) * 64;
    const float* xb = x + (size_t)b * CH * HWSZ + h * WW + w0;
    {
        const int w = t & 63, c0 = (t >> 6) * 16;
        #pragma unroll
        for (int jj = 0; jj < 16; ++jj)
            tile[c0 + jj][w] = xb[(size_t)(c0 + jj) * HWSZ + w];
    }
    __syncthreads();
    {
        const int c = t & 63, wq = t >> 6;
        __half* o = xT + ((size_t)b * HWSZ + h * WW + w0) * 64;
        #pragma unroll
        for (int jj = 0; jj < 16; ++jj) {
            const int w = wq * 16 + jj;
            o[(size_t)w * 64 + c] = __float2half(tile[c][w]);
        }
    }
}

// ---------------- Kernel A: offsets partials (8 ch x 2 rows per block, no atomics) ----------------
// part[cg][b][p] float4 raw conv sums, stored in d_out scratch.
__global__ __launch_bounds__(256) void offsets_kernel(
    const float* __restrict__ x,
    const float* __restrict__ w_rot,
    const float* __restrict__ w_str,
    const float* __restrict__ w_whl,
    float4* __restrict__ part)
{
    __shared__ float xs[8][4][WW];   // 16 KB
    const int t  = threadIdx.x;
    const int i  = blockIdx.x;       // 4096 blocks
    const int b  = i & 7;            // XCD-affine
    const int rp = (i >> 3) & 63;
    const int cg = i >> 9;           // 0..7
    const int h0 = rp * 2;
    const int c0 = cg * 8;
    const float* xb = x + (size_t)b * CH * HWSZ;
    #pragma unroll
    for (int jj = 0; jj < 4; ++jj) {
        const int u   = t + jj * 256;
        const int ch  = u >> 7;
        const int rem = u & 127;
        const int row = rem >> 5;
        const int w4  = (rem & 31) * 4;
        const int grow = h0 - 1 + row;
        float4 v = make_float4(0.f, 0.f, 0.f, 0.f);
        if (grow >= 0 && grow < HH)
            v = *(const float4*)&xb[((size_t)(c0 + ch) * HH + grow) * WW + w4];
        *(float4*)&xs[ch][row][w4] = v;
    }
    __syncthreads();
    const int r = t >> 7, w = t & 127;
    const int wl = max(w - 1, 0), wr2 = min(w + 1, WW - 1);
    const float ml = (w > 0) ? 1.f : 0.f, mr = (w < WW - 1) ? 1.f : 0.f;
    float a0 = 0.f, a1 = 0.f, a2 = 0.f, a3 = 0.f;
    #pragma unroll
    for (int ch = 0; ch < 8; ++ch) {
        const int cc = c0 + ch;
        #pragma unroll
        for (int dy = 0; dy < 3; ++dy) {
            const float* row_ = &xs[ch][r + dy][0];
            const float nl = row_[wl] * ml;
            const float nc = row_[w];
            const float nr = row_[wr2] * mr;
            const int d0 = cc * 9 + dy * 3;
            a0 = fmaf(nl, w_rot[d0 + 0], a0); a0 = fmaf(nc, w_rot[d0 + 1], a0); a0 = fmaf(nr, w_rot[d0 + 2], a0);
            a1 = fmaf(nl, w_rot[576 + d0 + 0], a1); a1 = fmaf(nc, w_rot[576 + d0 + 1], a1); a1 = fmaf(nr, w_rot[576 + d0 + 2], a1);
            a2 = fmaf(nl, w_str[d0 + 0], a2); a2 = fmaf(nc, w_str[d0 + 1], a2); a2 = fmaf(nr, w_str[d0 + 2], a2);
            a3 = fmaf(nl, w_whl[d0 + 0], a3); a3 = fmaf(nc, w_whl[d0 + 1], a3); a3 = fmaf(nr, w_whl[d0 + 2], a3);
        }
    }
    part[((size_t)cg * NB + b) * HWSZ + (h0 + r) * WW + w] = make_float4(a0, a1, a2, a3);
}

// ---------------- Kernel R: reduce partials -> final offs (sin,cos,wr*r,wr) ----------------
__global__ __launch_bounds__(256) void reduce_kernel(
    const float4* __restrict__ part,
    const float* __restrict__ b_rot, const float* __restrict__ b_str,
    const float* __restrict__ b_whl, float4* __restrict__ offs)
{
    const int i = blockIdx.x * 256 + threadIdx.x;   // < NB*HWSZ
    float4 s = make_float4(0.f, 0.f, 0.f, 0.f);
    #pragma unroll
    for (int cg = 0; cg < 8; ++cg) {
        const float4 p = part[(size_t)cg * NB * HWSZ + i];
        s.x += p.x; s.y += p.y; s.z += p.z; s.w += p.w;
    }
    float sv = s.x + b_rot[0], cv = s.y + b_rot[1];
    const float inv = 1.0f / sqrtf(sv * sv + cv * cv + 1e-6f);
    const float rr = tanhf(s.z + b_str[0]) * 1.25f + 1.75f;   // A,B
    const float wq = tanhf(s.w + b_whl[0]) * 1.0f + 2.0f;     // C,D
    offs[i] = make_float4(sv * inv, cv * inv, wq * rr, wq);
}

// ---------------- Kernel B: LDS-staged gather (fp16, swizzled) + MFMA ----------------
__global__ __launch_bounds__(256, 3) void deform_kernel(
    const __half* __restrict__ xT, const __half* __restrict__ wmT2,
    const float4* __restrict__ offs, float* __restrict__ out)
{
    __shared__ union {
        uint4 xs[RPX * 4];      // 784 px * 64 B (32 ch fp16) = 50176 B
        float ots[64][67];      // epilogue
    } sh;
    const int t  = threadIdx.x;
    const int wv = t >> 6;
    const int l  = t & 63;
    const int lm = l & 15;          // A-row (px) / B oc
    const int lg = l >> 4;          // 8-channel slab within group
    const int i  = blockIdx.x;      // 2048 blocks
    const int b  = i & 7;           // XCD-affine
    const int tile = i >> 3;        // 0..255
    const int w0 = (tile & 15) * 8;
    const int h0 = (tile >> 4) * 8;
    const int pi = wv * 16 + lm;    // local px 0..63
    const int h = h0 + (pi >> 3);
    const int w = w0 + (pi & 7);
    const float4 o4 = offs[(size_t)b * HWSZ + h * WW + w];
    const float sv = o4.x, cv = o4.y, av = o4.z, wvl = o4.w;
    const float hh  = (float)h;
    const float wwf = (float)w;
    const __half* xb = xT + (size_t)b * HWSZ * 64;

    // per-tap geometry hoisted: region index, step-pack, 4 broadcast half2 weights
    int ti[9], td[9];
    __half2 w2[9][4];
    #pragma unroll
    for (int k = 0; k < 9; ++k) {
        const float kyf = (float)(k / 3) - 1.f;
        const float kxf = (float)(k % 3) - 1.f;
        const float o0v = kyf * av;
        const float o1v = kxf * wvl;
        const float pyf = hh  + cv * o0v + sv * o1v;
        const float pxf = wwf - sv * o0v + cv * o1v;
        const float y0f = floorf(pyf), x0f = floorf(pxf);
        const float ly = pyf - y0f, lx = pxf - x0f;
        const int y0 = (int)y0f, x0i = (int)x0f;
        const int y1 = y0 + 1, x1 = x0i + 1;
        const bool vy0 = (y0 >= 0) && (y0 < HH);
        const bool vy1 = (y1 >= 0) && (y1 < HH);
        const bool vx0 = (x0i >= 0) && (x0i < WW);
        const bool vx1 = (x1 >= 0) && (x1 < WW);
        w2[k][0] = __float2half2_rn((1.f - ly) * (1.f - lx) * ((vy0 && vx0) ? 1.f : 0.f));
        w2[k][1] = __float2half2_rn((1.f - ly) * lx         * ((vy0 && vx1) ? 1.f : 0.f));
        w2[k][2] = __float2half2_rn(ly * (1.f - lx)         * ((vy1 && vx0) ? 1.f : 0.f));
        w2[k][3] = __float2half2_rn(ly * lx                 * ((vy1 && vx1) ? 1.f : 0.f));
        const int iy0 = min(max(y0, 0), HH - 1), iy1 = min(max(y1, 0), HH - 1);
        const int ix0 = min(max(x0i, 0), WW - 1), ix1 = min(max(x1, 0), WW - 1);
        ti[k] = (iy0 - (h0 - 10)) * RG + (ix0 - (w0 - 10));
        td[k] = (ix1 - ix0) | ((iy1 - iy0) << 1);
    }

    f32x4_t acc0 = {0.f, 0.f, 0.f, 0.f};
    f32x4_t acc1 = acc0, acc2 = acc0, acc3 = acc0;

    for (int g = 0; g < 2; ++g) {
        __syncthreads();
        // stage 28x28 region, 32 ch of group g (64 B/px), XOR-swizzled slots
        for (int u = t; u < RPX * 4; u += 256) {
            const int pxu = u >> 2, q = u & 3;
            const int lr = pxu / RG;
            const int lc = pxu - lr * RG;
            const int gy = min(max(h0 - 10 + lr, 0), HH - 1);
            const int gx = min(max(w0 - 10 + lc, 0), WW - 1);
            sh.xs[pxu * 4 + (q ^ (pxu & 3))] =
                *(const uint4*)(xb + (size_t)(gy * WW + gx) * 64 + g * 32 + q * 8);
        }
        __syncthreads();
        const int cb0 = g * 32 + lg * 8;
        #pragma unroll
        for (int k = 0; k < 9; ++k) {
            const int i00 = ti[k];
            const int dxx = td[k] & 1;
            const int dyy = (td[k] >> 1) * RG;
            const int i01 = i00 + dxx;
            const int i10 = i00 + dyy;
            const int i11 = i10 + dxx;
            union Q { uint4 q; __half2 h2[4]; };
            Q q00, q01, q10, q11;
            q00.q = sh.xs[i00 * 4 + (lg ^ (i00 & 3))];
            q01.q = sh.xs[i01 * 4 + (lg ^ (i01 & 3))];
            q10.q = sh.xs[i10 * 4 + (lg ^ (i10 & 3))];
            q11.q = sh.xs[i11 * 4 + (lg ^ (i11 & 3))];
            union { __half2 h2[4]; f16x8 v; } af;
            #pragma unroll
            for (int j = 0; j < 4; ++j) {
                af.h2[j] = __hfma2(q00.h2[j], w2[k][0],
                           __hfma2(q01.h2[j], w2[k][1],
                           __hfma2(q10.h2[j], w2[k][2],
                           __hmul2(q11.h2[j], w2[k][3]))));
            }
            const __half* wp = wmT2 + ((size_t)k * 64 + lm) * 64 + cb0;
            const f16x8 bf0 = *(const f16x8*)(wp);
            const f16x8 bf1 = *(const f16x8*)(wp + 1024);
            const f16x8 bf2v = *(const f16x8*)(wp + 2048);
            const f16x8 bf3 = *(const f16x8*)(wp + 3072);
            acc0 = __builtin_amdgcn_mfma_f32_16x16x32_f16(af.v, bf0,  acc0, 0, 0, 0);
            acc1 = __builtin_amdgcn_mfma_f32_16x16x32_f16(af.v, bf1,  acc1, 0, 0, 0);
            acc2 = __builtin_amdgcn_mfma_f32_16x16x32_f16(af.v, bf2v, acc2, 0, 0, 0);
            acc3 = __builtin_amdgcn_mfma_f32_16x16x32_f16(af.v, bf3,  acc3, 0, 0, 0);
        }
    }
    __syncthreads();
    // epilogue: C/D layout col=lane&15 (oc), row=(lane>>4)*4+reg (local px)
    const int pxw = wv * 16 + lg * 4;
    #pragma unroll
    for (int rg2 = 0; rg2 < 4; ++rg2) {
        sh.ots[pxw + rg2][ 0 + lm] = acc0[rg2];
        sh.ots[pxw + rg2][16 + lm] = acc1[rg2];
        sh.ots[pxw + rg2][32 + lm] = acc2[rg2];
        sh.ots[pxw + rg2][48 + lm] = acc3[rg2];
    }
    __syncthreads();
    const int oo = t >> 2;
    const int q  = (t & 3) * 16;
    #pragma unroll
    for (int j2 = 0; j2 < 4; ++j2) {
        const int px = q + j2 * 4;
        float4 v = make_float4(sh.ots[px + 0][oo], sh.ots[px + 1][oo],
                               sh.ots[px + 2][oo], sh.ots[px + 3][oo]);
        *(float4*)&out[((size_t)b * OC + oo) * HWSZ +
                       (h0 + (px >> 3)) * WW + w0 + (px & 7)] = v;
    }
}

extern "C" void kernel_launch(void* const* d_in, const int* in_sizes, int n_in,
                              void* d_out, int out_size, void* d_ws, size_t ws_size,
                              hipStream_t stream)
{
    const float* x      = (const float*)d_in[0];
    const float* w_main = (const float*)d_in[1];
    const float* w_rot  = (const float*)d_in[2];
    const float* b_rot  = (const float*)d_in[3];
    const float* w_str  = (const float*)d_in[4];
    const float* b_str  = (const float*)d_in[5];
    const float* w_whl  = (const float*)d_in[6];
    const float* b_whl  = (const float*)d_in[7];
    float* out = (float*)d_out;

    char* ws = (char*)d_ws;
    __half*  xT   = (__half*)ws;
    float4*  offs = (float4*)(ws + XT_BYTES);
    __half*  wmT2 = (__half*)(ws + XT_BYTES + OFFS_BYTES);
    float4*  part = (float4*)d_out;   // 16.8 MB partial scratch inside 33.5 MB out

    transpose_kernel<<<dim3(2057), 256, 0, stream>>>(x, w_main, xT, wmT2);
    offsets_kernel<<<dim3(4096), 256, 0, stream>>>(x, w_rot, w_str, w_whl, part);
    reduce_kernel<<<dim3(NB * HWSZ / 256), 256, 0, stream>>>(
        part, b_rot, b_str, b_whl, offs);
    deform_kernel<<<dim3(2048), 256, 0, stream>>>(xT, wmT2, offs, out);
}